// Round 11
// baseline (635.219 us; speedup 1.0000x reference)
//
#include <hip/hip_runtime.h>
#include <math.h>

#define MU1   256
#define H     64
#define H2    128
#define SKIPC 256
#define NL    24
#define LF    80
#define UPK   4
#define REP   75
#define BB    2
#define LLEN  64
#define LL    19200

using bf16x8 = __attribute__((ext_vector_type(8))) short;
using bf16x4 = __attribute__((ext_vector_type(4))) short;
using f32x4  = __attribute__((ext_vector_type(4))) float;

__device__ __forceinline__ float b2f(short s) {
    union { unsigned u; float f; } v; v.u = ((unsigned)(unsigned short)s) << 16; return v.f;
}
__device__ __forceinline__ short f2b(float f) {
    union { float f; unsigned u; } v; v.f = f;
    unsigned r = (v.u + 0x7fff + ((v.u >> 16) & 1)) >> 16;
    return (short)r;
}

// ---------------------------------------------------------------- prep ----
__global__ __launch_bounds__(256) void prep_kernel(
    const float* __restrict__ dil_W,  const float* __restrict__ skip_W,
    const float* __restrict__ res_W,  const float* __restrict__ embed_W,
    const float* __restrict__ embed_b,const float* __restrict__ cond_W,
    const float* __restrict__ out_W1, const float* __restrict__ out_W2,
    const float* __restrict__ skip_b,
    short* __restrict__ dil_Wb, short* __restrict__ skip_Wb,
    short* __restrict__ res_Wb, short* __restrict__ embed_allb,
    float* __restrict__ cond_Wt, short* __restrict__ W1b,
    short* __restrict__ W2b, float* __restrict__ sbsum)
{
    int idx = blockIdx.x * 256 + threadIdx.x;
    const int n1 = NL * 2 * H2 * H;     // dil_Wb[i][k][o][c]
    const int n2 = NL * SKIPC * H;      // skip_Wb[i][s][c]
    const int n3 = (NL - 1) * H * H;    // res_Wb[i][o][c]
    const int n4 = MU1 * H;             // embed_allb[g][h]
    const int n5 = LF * NL * H2;        // cond_Wt[c][o]
    const int n6 = MU1 * SKIPC;
    const int n7 = MU1 * MU1;
    if (idx < n1) {
        int c = idx & 63; int o = (idx >> 6) & 127;
        int k = (idx >> 13) & 1; int i = idx >> 14;
        dil_Wb[idx] = f2b(dil_W[((i * H2 + o) * H + c) * 2 + k]);
        return;
    }
    idx -= n1;
    if (idx < n2) { skip_Wb[idx] = f2b(skip_W[idx]); return; }
    idx -= n2;
    if (idx < n3) { res_Wb[idx] = f2b(res_W[idx]); return; }
    idx -= n3;
    if (idx < n4) {
        int h = idx & 63; int g = idx >> 6;
        embed_allb[idx] = f2b(embed_W[h * MU1 + g] + embed_b[h]);
        return;
    }
    idx -= n4;
    if (idx < n5) {
        int o = idx % (NL * H2); int c = idx / (NL * H2);
        cond_Wt[idx] = cond_W[o * LF + c];
        return;
    }
    idx -= n5;
    if (idx < n6) { W1b[idx] = f2b(out_W1[idx]); return; }
    idx -= n6;
    if (idx < n7) { W2b[idx] = f2b(out_W2[idx]); return; }
    idx -= n7;
    if (idx < SKIPC) {
        float a = 0.f;
        for (int i = 0; i < NL; i++) a += skip_b[i * SKIPC + idx];
        sbsum[idx] = a;
        return;
    }
}

// --------------------------------------------------------------- embed ----
__global__ __launch_bounds__(256) void embed_kernel(
    const int* __restrict__ gold, const short* __restrict__ eW,
    short* __restrict__ sig)
{
    int idx = blockIdx.x * 256 + threadIdx.x;
    if (idx >= BB * LL * 8) return;
    int ch = idx & 7; int bt = idx >> 3;
    int g = gold[bt];
    *(bf16x8*)(sig + (size_t)bt * H + ch * 8) = *(const bf16x8*)(eW + g * H + ch * 8);
}

// ---------------------------------------------------------------- cond ----
__global__ __launch_bounds__(256) void cond_kernel(
    const float* __restrict__ lf, const float* __restrict__ up_W,
    const float* __restrict__ up_b, const float* __restrict__ cond_Wt,
    const float* __restrict__ cond_b, const float* __restrict__ dil_b,
    float* __restrict__ condS)
{
    __shared__ float s_up[LF];
    int j = blockIdx.x;
    int ot = blockIdx.y;
    int b = blockIdx.z;
    int frame = j >> 2, k = j & 3;
    int tid = threadIdx.x;
    if (tid < LF) {
        float a = up_b[tid];
        const float* lfr = lf + (b * LLEN + frame) * LF;
        #pragma unroll 8
        for (int c = 0; c < LF; ++c) a += lfr[c] * up_W[(c * LF + tid) * UPK + k];
        s_up[tid] = a;
    }
    __syncthreads();
    int o = ot * 256 + tid;
    float a = cond_b[o] + dil_b[o];
    #pragma unroll 8
    for (int c = 0; c < LF; ++c) a += cond_Wt[c * 3072 + o] * s_up[c];
    condS[((size_t)(b * 256 + j)) * 3072 + o] = a;
}

// ------------------------- fused layer pair, TT=96, 512 threads ----
// Same tile/LDS as the measured-best R4 pair, but 8 waves/block:
// 2 blocks/CU -> 16 waves/CU (4/SIMD) for 2x latency hiding.
// A: wave w -> Mtile w (rows 16w..16w+16 of the 128-row A window).
// B: wave w -> Mtile triple (w>>2)*3.. x channel quad (w&3).
template<int DA, int DB, bool LASTPAIR>
__global__ __launch_bounds__(512) void pair_mfma(
    const short* __restrict__ sig_in, short* __restrict__ sig_out,
    short* __restrict__ z12,
    const short* __restrict__ dil_Wb_all,
    const short* __restrict__ res_Wb_all,
    const float* __restrict__ res_b_all,
    const float* __restrict__ condS,
    int p, int slot)
{
    __shared__ __align__(16) short sa[144][72];   // input rows [t0-48, t0+96)
    __shared__ __align__(16) short sb[128][72];   // A output rows [t0-32, t0+96)
    __shared__ __align__(16) short sz[128][72];   // z scratch
    __shared__ float scond[2][3][128];

    const int iA = 2 * p, iB = 2 * p + 1;
    const int b = blockIdx.y;
    const int t0 = blockIdx.x * 96;
    const int tid = threadIdx.x;
    const int w = tid >> 6;            // 0..7
    const int lane = tid & 63;
    const int lr = lane & 15, lg = lane >> 4;
    const int c0 = (t0 >= 32) ? (t0 - 32) / 75 : 0;

    // ---- stage input + cond ----
    {
        const short* basein = sig_in + (size_t)b * LL * H;
        #pragma unroll
        for (int it = 0; it < 3; ++it) {
            int task = tid + it * 512;
            if (task < 1152) {
                int r = task >> 3, ch = task & 7;
                int t = t0 - 48 + r;
                bf16x8 v = {};
                if (t >= 0) v = *(const bf16x8*)(basein + (size_t)t * H + ch * 8);
                *(bf16x8*)&sa[r][ch * 8] = v;
            }
        }
        #pragma unroll
        for (int it = 0; it < 2; ++it) {
            int task = tid + it * 512;      // 768 = 2 sel x 3 col x 128
            if (task < 768) {
                int sel = task >= 384;
                int cj = (task - sel * 384) >> 7;
                int o = task & 127;
                int col = c0 + cj; col = col > 255 ? 255 : col;
                scond[sel][cj][o] = condS[((size_t)(b * 256 + col)) * 3072 + (iA + sel) * 128 + o];
            }
        }
    }
    __syncthreads();

    // ---- A gated GEMM: wave w -> Mtile w (of 8), N=128, K=128 ----
    {
        const short* dW = dil_Wb_all + (size_t)iA * 2 * H2 * H;
        f32x4 acc[8];
        #pragma unroll
        for (int n = 0; n < 8; ++n) acc[n] = (f32x4){0.f, 0.f, 0.f, 0.f};
        int rc = 16 + 16 * w + lr;
        bf16x8 af[4];
        af[0] = *(const bf16x8*)&sa[rc - DA][lg * 8];
        af[1] = *(const bf16x8*)&sa[rc - DA][32 + lg * 8];
        af[2] = *(const bf16x8*)&sa[rc][lg * 8];
        af[3] = *(const bf16x8*)&sa[rc][32 + lg * 8];
        #pragma unroll
        for (int n = 0; n < 8; ++n)
            #pragma unroll
            for (int kk = 0; kk < 4; ++kk) {
                bf16x8 bw = *(const bf16x8*)(dW + (((kk >> 1) * H2 + 16 * n + lr) * H) + (kk & 1) * 32 + lg * 8);
                acc[n] = __builtin_amdgcn_mfma_f32_16x16x32_bf16(af[kk], bw, acc[n], 0, 0, 0);
            }
        #pragma unroll
        for (int n = 0; n < 4; ++n)
            #pragma unroll
            for (int r = 0; r < 4; ++r) {
                int zrow = 16 * w + 4 * lg + r;      // in [0,128)
                int t = t0 - 32 + zrow;
                int o = 16 * n + lr;
                short zb = 0;
                if (t >= 0) {
                    int ci = t / REP - c0;
                    float av = acc[n][r] + scond[0][ci][o];
                    float gv = acc[n + 4][r] + scond[0][ci][64 + o];
                    float th = 1.f - 2.f / (__expf(2.f * av) + 1.f);
                    float sg = 1.f / (1.f + __expf(-gv));
                    zb = f2b(th * sg);
                }
                sz[zrow][o] = zb;
            }
    }
    __syncthreads();

    // z_A -> z12 slot, sub 0 (rows [t0,t0+96) = sz rows [32,128))
    #pragma unroll
    for (int it = 0; it < 2; ++it) {
        int task = tid + it * 512;
        if (task < 768) {
            int r = task >> 3, ch = task & 7;
            *(bf16x8*)(z12 + ((size_t)((slot * BB + b) * LL) + t0 + r) * 128 + ch * 8)
                = *(const bf16x8*)&sz[32 + r][ch * 8];
        }
    }

    // ---- A residual: sb = sa + z @ rW + rb (wave w -> row block w) ----
    {
        const short* rW = res_Wb_all + (size_t)iA * H * H;
        const float* rb_ = res_b_all + (size_t)iA * H;
        f32x4 rac[4];
        #pragma unroll
        for (int n = 0; n < 4; ++n) rac[n] = (f32x4){0.f, 0.f, 0.f, 0.f};
        int row = 16 * w + lr;
        bf16x8 za0 = *(const bf16x8*)&sz[row][lg * 8];
        bf16x8 za1 = *(const bf16x8*)&sz[row][32 + lg * 8];
        #pragma unroll
        for (int n = 0; n < 4; ++n) {
            bf16x8 bw0 = *(const bf16x8*)(rW + (16 * n + lr) * H + lg * 8);
            bf16x8 bw1 = *(const bf16x8*)(rW + (16 * n + lr) * H + 32 + lg * 8);
            rac[n] = __builtin_amdgcn_mfma_f32_16x16x32_bf16(za0, bw0, rac[n], 0, 0, 0);
            rac[n] = __builtin_amdgcn_mfma_f32_16x16x32_bf16(za1, bw1, rac[n], 0, 0, 0);
        }
        #pragma unroll
        for (int n = 0; n < 4; ++n) {
            float rbv = rb_[16 * n + lr];
            #pragma unroll
            for (int r = 0; r < 4; ++r) {
                int srow = 16 * w + 4 * lg + r;      // in [0,128)
                int t = t0 - 32 + srow;
                int c = 16 * n + lr;
                short vb = 0;
                if (t >= 0) vb = f2b(b2f(sa[srow + 16][c]) + rac[n][r] + rbv);
                sb[srow][c] = vb;
            }
        }
    }
    __syncthreads();

    // ---- B gated GEMM: wave w -> Mtile triple (w>>2), channel quad (w&3) ----
    {
        const short* dW = dil_Wb_all + (size_t)iB * 2 * H2 * H;
        const int mh = w >> 2, nq = w & 3;
        f32x4 accF[3], accG[3];
        #pragma unroll
        for (int m = 0; m < 3; ++m) { accF[m] = (f32x4){0.f,0.f,0.f,0.f}; accG[m] = (f32x4){0.f,0.f,0.f,0.f}; }
        bf16x8 bwF[4], bwG[4];
        int oF = 16 * nq + lr;
        #pragma unroll
        for (int kk = 0; kk < 4; ++kk) {
            bwF[kk] = *(const bf16x8*)(dW + (((kk >> 1) * H2 + oF) * H) + (kk & 1) * 32 + lg * 8);
            bwG[kk] = *(const bf16x8*)(dW + (((kk >> 1) * H2 + 64 + oF) * H) + (kk & 1) * 32 + lg * 8);
        }
        #pragma unroll
        for (int m = 0; m < 3; ++m) {
            int rc = 32 + 16 * (3 * mh + m) + lr;
            bf16x8 af[4];
            af[0] = *(const bf16x8*)&sb[rc - DB][lg * 8];
            af[1] = *(const bf16x8*)&sb[rc - DB][32 + lg * 8];
            af[2] = *(const bf16x8*)&sb[rc][lg * 8];
            af[3] = *(const bf16x8*)&sb[rc][32 + lg * 8];
            #pragma unroll
            for (int kk = 0; kk < 4; ++kk)
                accF[m] = __builtin_amdgcn_mfma_f32_16x16x32_bf16(af[kk], bwF[kk], accF[m], 0, 0, 0);
            #pragma unroll
            for (int kk = 0; kk < 4; ++kk)
                accG[m] = __builtin_amdgcn_mfma_f32_16x16x32_bf16(af[kk], bwG[kk], accG[m], 0, 0, 0);
        }
        #pragma unroll
        for (int m = 0; m < 3; ++m)
            #pragma unroll
            for (int r = 0; r < 4; ++r) {
                int relt = 16 * (3 * mh + m) + 4 * lg + r;   // in [0,96)
                int t = t0 + relt;
                int o = 16 * nq + lr;
                int ci = t / REP - c0;
                float av = accF[m][r] + scond[1][ci][o];
                float gv = accG[m][r] + scond[1][ci][64 + o];
                float th = 1.f - 2.f / (__expf(2.f * av) + 1.f);
                float sg = 1.f / (1.f + __expf(-gv));
                sz[relt][o] = f2b(th * sg);
            }
    }
    __syncthreads();

    // z_B -> z12 slot, sub 1 (rows [0,96))
    #pragma unroll
    for (int it = 0; it < 2; ++it) {
        int task = tid + it * 512;
        if (task < 768) {
            int r = task >> 3, ch = task & 7;
            *(bf16x8*)(z12 + ((size_t)((slot * BB + b) * LL) + t0 + r) * 128 + 64 + ch * 8)
                = *(const bf16x8*)&sz[r][ch * 8];
        }
    }

    // ---- B residual -> sig_out: wave w -> Mtile triple (w>>2), Ntile (w&3) ----
    if (!LASTPAIR) {
        const short* rW = res_Wb_all + (size_t)iB * H * H;
        const float* rb_ = res_b_all + (size_t)iB * H;
        const int mh = w >> 2, nq = w & 3;
        int c = 16 * nq + lr;
        f32x4 rac[3];
        #pragma unroll
        for (int m = 0; m < 3; ++m) rac[m] = (f32x4){0.f, 0.f, 0.f, 0.f};
        bf16x8 bwR0 = *(const bf16x8*)(rW + c * H + lg * 8);
        bf16x8 bwR1 = *(const bf16x8*)(rW + c * H + 32 + lg * 8);
        #pragma unroll
        for (int m = 0; m < 3; ++m) {
            int row = 16 * (3 * mh + m) + lr;
            bf16x8 z0 = *(const bf16x8*)&sz[row][lg * 8];
            bf16x8 z1 = *(const bf16x8*)&sz[row][32 + lg * 8];
            rac[m] = __builtin_amdgcn_mfma_f32_16x16x32_bf16(z0, bwR0, rac[m], 0, 0, 0);
            rac[m] = __builtin_amdgcn_mfma_f32_16x16x32_bf16(z1, bwR1, rac[m], 0, 0, 0);
        }
        float rbv = rb_[c];
        #pragma unroll
        for (int m = 0; m < 3; ++m)
            #pragma unroll
            for (int r = 0; r < 4; ++r) {
                int relt = 16 * (3 * mh + m) + 4 * lg + r;   // in [0,96)
                sa[relt][c] = f2b(b2f(sb[relt + 32][c]) + rac[m][r] + rbv);
            }
        __syncthreads();
        #pragma unroll
        for (int it = 0; it < 2; ++it) {
            int task = tid + it * 512;
            if (task < 768) {
                int r = task >> 3, ch = task & 7;
                *(bf16x8*)(sig_out + ((size_t)(b * LL) + t0 + r) * H + ch * 8)
                    = *(const bf16x8*)&sa[r][ch * 8];
            }
        }
    }
}

// -------------------- slot-layout skip GEMM (12 layers, K=768) ----
// skipS[b][t][s] (+)= sum over 6 slots of z12[slot][b][t][0:128] @ W
template<bool G0>
__global__ __launch_bounds__(256) void skip_slot(
    const short* __restrict__ z12, const short* __restrict__ sWb,
    float* __restrict__ skipS, int base)
{
    __shared__ __align__(16) short s_a[2][64][136];
    const int b = blockIdx.y;
    const int t0 = blockIdx.x * 64;
    const int tid = threadIdx.x;
    const int w = tid >> 6;
    const int lane = tid & 63;
    const int lr = lane & 15, lg = lane >> 4;

    f32x4 acc[4][4];
    #pragma unroll
    for (int mt = 0; mt < 4; ++mt)
        #pragma unroll
        for (int nt = 0; nt < 4; ++nt) acc[mt][nt] = (f32x4){0.f, 0.f, 0.f, 0.f};

    #pragma unroll
    for (int it = 0; it < 4; ++it) {
        int task = tid + it * 256;
        int r = task >> 4, ch = task & 15;
        *(bf16x8*)&s_a[0][r][ch * 8] =
            *(const bf16x8*)(z12 + ((size_t)(b * LL) + t0 + r) * 128 + ch * 8);
    }
    __syncthreads();

    for (int ck = 0; ck < 6; ++ck) {
        if (ck < 5) {
            #pragma unroll
            for (int it = 0; it < 4; ++it) {
                int task = tid + it * 256;
                int r = task >> 4, ch = task & 15;
                *(bf16x8*)&s_a[(ck + 1) & 1][r][ch * 8] =
                    *(const bf16x8*)(z12 + ((size_t)(((ck + 1) * BB + b) * LL) + t0 + r) * 128 + ch * 8);
            }
        }
        const short (*buf)[136] = s_a[ck & 1];
        #pragma unroll
        for (int kk = 0; kk < 4; ++kk) {
            bf16x8 afr[4];
            #pragma unroll
            for (int mt = 0; mt < 4; ++mt)
                afr[mt] = *(const bf16x8*)&buf[16 * mt + lr][32 * kk + 8 * lg];
            int layer = base + 2 * ck + (kk >> 1);
            #pragma unroll
            for (int nt = 0; nt < 4; ++nt) {
                bf16x8 bw = *(const bf16x8*)(sWb +
                    ((size_t)(layer * SKIPC + 64 * w + 16 * nt + lr)) * H + (kk & 1) * 32 + 8 * lg);
                #pragma unroll
                for (int mt = 0; mt < 4; ++mt)
                    acc[mt][nt] = __builtin_amdgcn_mfma_f32_16x16x32_bf16(afr[mt], bw, acc[mt][nt], 0, 0, 0);
            }
        }
        __syncthreads();
    }

    #pragma unroll
    for (int mt = 0; mt < 4; ++mt)
        #pragma unroll
        for (int nt = 0; nt < 4; ++nt) {
            int s = 64 * w + 16 * nt + lr;
            #pragma unroll
            for (int reg = 0; reg < 4; ++reg) {
                int t = t0 + 16 * mt + 4 * lg + reg;
                float* p = skipS + ((size_t)(b * LL + t)) * SKIPC + s;
                float v = acc[mt][nt][reg];
                if (!G0) v += *p;
                *p = v;
            }
        }
}

// ------------------------------------------- head, TT=32 (600 blocks) ----
__global__ __launch_bounds__(256) void head_mfma(
    const float* __restrict__ skipS, const float* __restrict__ sbsum,
    const short* __restrict__ W1b, const short* __restrict__ W2b,
    float* __restrict__ out)
{
    __shared__ __align__(16) unsigned char smem[18432];
    short (*s_x)[264] = (short(*)[264])smem;   // 32x264 bf16
    float (*s_o)[36]  = (float(*)[36])smem;    // 128x36 f32
    __shared__ float s_red[4][32];
    __shared__ float s_sb[256];

    const int b = blockIdx.y;
    const int t0 = blockIdx.x * 32;
    const int tid = threadIdx.x;
    const int w = tid >> 6;
    const int lane = tid & 63;
    const int lr = lane & 15, lg = lane >> 4;

    s_sb[tid] = sbsum[tid];
    __syncthreads();

    #pragma unroll
    for (int it = 0; it < 8; ++it) {
        int task = tid + it * 256;
        int r = task >> 6, c4 = task & 63;
        f32x4 v = *(const f32x4*)(skipS + ((size_t)(b * LL + t0 + r)) * SKIPC + c4 * 4);
        bf16x4 o;
        #pragma unroll
        for (int j = 0; j < 4; ++j) o[j] = f2b(fmaxf(v[j] + s_sb[c4 * 4 + j], 0.f));
        *(bf16x4*)&s_x[r][c4 * 4] = o;
    }
    __syncthreads();

    f32x4 acc1[2][4];
    #pragma unroll
    for (int mt = 0; mt < 2; ++mt)
        #pragma unroll
        for (int nt = 0; nt < 4; ++nt) acc1[mt][nt] = (f32x4){0.f, 0.f, 0.f, 0.f};
    #pragma unroll
    for (int kk = 0; kk < 8; ++kk) {
        bf16x8 afr[2];
        #pragma unroll
        for (int mt = 0; mt < 2; ++mt)
            afr[mt] = *(const bf16x8*)&s_x[16 * mt + lr][32 * kk + 8 * lg];
        #pragma unroll
        for (int nt = 0; nt < 4; ++nt) {
            bf16x8 bw = *(const bf16x8*)(W1b + ((size_t)(64 * w + 16 * nt + lr)) * MU1 + 32 * kk + 8 * lg);
            #pragma unroll
            for (int mt = 0; mt < 2; ++mt)
                acc1[mt][nt] = __builtin_amdgcn_mfma_f32_16x16x32_bf16(afr[mt], bw, acc1[mt][nt], 0, 0, 0);
        }
    }
    __syncthreads();
    #pragma unroll
    for (int mt = 0; mt < 2; ++mt)
        #pragma unroll
        for (int nt = 0; nt < 4; ++nt)
            #pragma unroll
            for (int reg = 0; reg < 4; ++reg) {
                int tl = 16 * mt + 4 * lg + reg;
                int o = 64 * w + 16 * nt + lr;
                s_x[tl][o] = f2b(fmaxf(acc1[mt][nt][reg], 0.f));
            }
    __syncthreads();

    f32x4 acc2[2][4];
    #pragma unroll
    for (int mt = 0; mt < 2; ++mt)
        #pragma unroll
        for (int nt = 0; nt < 4; ++nt) acc2[mt][nt] = (f32x4){0.f, 0.f, 0.f, 0.f};
    #pragma unroll
    for (int kk = 0; kk < 8; ++kk) {
        bf16x8 afr[2];
        #pragma unroll
        for (int mt = 0; mt < 2; ++mt)
            afr[mt] = *(const bf16x8*)&s_x[16 * mt + lr][32 * kk + 8 * lg];
        #pragma unroll
        for (int nt = 0; nt < 4; ++nt) {
            bf16x8 bw = *(const bf16x8*)(W2b + ((size_t)(64 * w + 16 * nt + lr)) * MU1 + 32 * kk + 8 * lg);
            #pragma unroll
            for (int mt = 0; mt < 2; ++mt)
                acc2[mt][nt] = __builtin_amdgcn_mfma_f32_16x16x32_bf16(afr[mt], bw, acc2[mt][nt], 0, 0, 0);
        }
    }

    float mv[2][4];
    #pragma unroll
    for (int mt = 0; mt < 2; ++mt)
        #pragma unroll
        for (int reg = 0; reg < 4; ++reg) {
            float m = -3.4e38f;
            #pragma unroll
            for (int nt = 0; nt < 4; ++nt) m = fmaxf(m, acc2[mt][nt][reg]);
            #pragma unroll
            for (int off = 1; off <= 8; off <<= 1) m = fmaxf(m, __shfl_xor(m, off));
            int tl = 16 * mt + 4 * lg + reg;
            if (lr == 0) s_red[w][tl] = m;
        }
    __syncthreads();
    #pragma unroll
    for (int mt = 0; mt < 2; ++mt)
        #pragma unroll
        for (int reg = 0; reg < 4; ++reg) {
            int tl = 16 * mt + 4 * lg + reg;
            mv[mt][reg] = fmaxf(fmaxf(s_red[0][tl], s_red[1][tl]), fmaxf(s_red[2][tl], s_red[3][tl]));
        }
    __syncthreads();
    #pragma unroll
    for (int mt = 0; mt < 2; ++mt)
        #pragma unroll
        for (int reg = 0; reg < 4; ++reg) {
            float s = 0.f;
            #pragma unroll
            for (int nt = 0; nt < 4; ++nt) s += __expf(acc2[mt][nt][reg] - mv[mt][reg]);
            #pragma unroll
            for (int off = 1; off <= 8; off <<= 1) s += __shfl_xor(s, off);
            int tl = 16 * mt + 4 * lg + reg;
            if (lr == 0) s_red[w][tl] = s;
        }
    __syncthreads();
    #pragma unroll
    for (int mt = 0; mt < 2; ++mt)
        #pragma unroll
        for (int reg = 0; reg < 4; ++reg) {
            int tl = 16 * mt + 4 * lg + reg;
            float denom = s_red[0][tl] + s_red[1][tl] + s_red[2][tl] + s_red[3][tl];
            mv[mt][reg] = mv[mt][reg] + __logf(denom);
        }
    __syncthreads();

    #pragma unroll
    for (int pass = 0; pass < 2; ++pass) {
        if ((w >> 1) == pass) {
            #pragma unroll
            for (int mt = 0; mt < 2; ++mt)
                #pragma unroll
                for (int nt = 0; nt < 4; ++nt)
                    #pragma unroll
                    for (int reg = 0; reg < 4; ++reg) {
                        int ch = 64 * (w & 1) + 16 * nt + lr;
                        int tl = 16 * mt + 4 * lg + reg;
                        s_o[ch][tl] = acc2[mt][nt][reg] - mv[mt][reg];
                    }
        }
        __syncthreads();
        {
            int row = tid >> 1, half = tid & 1;
            float* op = out + ((size_t)(b * MU1 + pass * 128 + row)) * LL + t0 + half * 16;
            #pragma unroll
            for (int k = 0; k < 4; ++k)
                *(f32x4*)(op + 4 * k) = *(const f32x4*)&s_o[row][half * 16 + 4 * k];
        }
        __syncthreads();
    }
}

// -------------------------------------------------------------- launch ----
extern "C" void kernel_launch(void* const* d_in, const int* in_sizes, int n_in,
                              void* d_out, int out_size, void* d_ws, size_t ws_size,
                              hipStream_t stream)
{
    const float* lf      = (const float*)d_in[0];
    const int*   gold    = (const int*)  d_in[1];
    const float* embed_W = (const float*)d_in[2];
    const float* embed_b = (const float*)d_in[3];
    const float* up_W    = (const float*)d_in[4];
    const float* up_b    = (const float*)d_in[5];
    const float* cond_W  = (const float*)d_in[6];
    const float* cond_b  = (const float*)d_in[7];
    const float* dil_W   = (const float*)d_in[8];
    const float* dil_b   = (const float*)d_in[9];
    const float* skip_W  = (const float*)d_in[10];
    const float* skip_b  = (const float*)d_in[11];
    const float* res_W   = (const float*)d_in[12];
    const float* res_b   = (const float*)d_in[13];
    const float* W1      = (const float*)d_in[14];
    const float* W2      = (const float*)d_in[15];
    float* out = (float*)d_out;

    unsigned char* p = (unsigned char*)d_ws;
    short* sigA      = (short*)p; p += (size_t)BB * LL * H * 2;          // 4.9 MB
    short* sigB      = (short*)p; p += (size_t)BB * LL * H * 2;          // 4.9 MB
    short* z12       = (short*)p; p += (size_t)6 * BB * LL * 128 * 2;    // 29.5 MB
    float* skipS     = (float*)p; p += (size_t)BB * LL * SKIPC * 4;      // 39.3 MB
    float* condS     = (float*)p; p += (size_t)BB * 256 * NL * H2 * 4;   // 6.3 MB
    short* dil_Wb    = (short*)p; p += (size_t)NL * 2 * H2 * H * 2;
    short* skip_Wb   = (short*)p; p += (size_t)NL * SKIPC * H * 2;
    short* res_Wb    = (short*)p; p += (size_t)(NL - 1) * H * H * 2;
    short* embed_allb= (short*)p; p += (size_t)MU1 * H * 2;
    float* cond_Wt   = (float*)p; p += (size_t)LF * NL * H2 * 4;
    short* W1b       = (short*)p; p += (size_t)MU1 * SKIPC * 2;
    short* W2b       = (short*)p; p += (size_t)MU1 * MU1 * 2;
    float* sbsum     = (float*)p; p += (size_t)SKIPC * 4;

    const int prep_n = NL*2*H2*H + NL*SKIPC*H + (NL-1)*H*H + MU1*H + LF*NL*H2 + MU1*SKIPC + MU1*MU1 + SKIPC;
    prep_kernel<<<(prep_n + 255) / 256, 256, 0, stream>>>(
        dil_W, skip_W, res_W, embed_W, embed_b, cond_W, W1, W2, skip_b,
        dil_Wb, skip_Wb, res_Wb, embed_allb, cond_Wt, W1b, W2b, sbsum);

    embed_kernel<<<(BB * LL * 8 + 255) / 256, 256, 0, stream>>>(gold, embed_allb, sigA);

    cond_kernel<<<dim3(256, 12, BB), 256, 0, stream>>>(lf, up_W, up_b, cond_Wt, cond_b, dil_b, condS);

    short* si = sigA;
    short* so = sigB;
    dim3 pgrid(LL / 96, BB);   // 200 x 2, 512-thread blocks
    dim3 sgrid(LL / 64, BB);   // 300 x 2
    for (int pp = 0; pp < 12; ++pp) {
        int slot = pp % 6;
        int r3 = pp % 3;
        if (r3 == 0)
            pair_mfma<1, 2, false><<<pgrid, 512, 0, stream>>>(si, so, z12, dil_Wb, res_Wb, res_b, condS, pp, slot);
        else if (r3 == 1)
            pair_mfma<4, 8, false><<<pgrid, 512, 0, stream>>>(si, so, z12, dil_Wb, res_Wb, res_b, condS, pp, slot);
        else if (pp == 11)
            pair_mfma<16, 32, true><<<pgrid, 512, 0, stream>>>(si, so, z12, dil_Wb, res_Wb, res_b, condS, pp, slot);
        else
            pair_mfma<16, 32, false><<<pgrid, 512, 0, stream>>>(si, so, z12, dil_Wb, res_Wb, res_b, condS, pp, slot);
        short* tmp = si; si = so; so = tmp;

        if (pp == 5)
            skip_slot<true><<<sgrid, 256, 0, stream>>>(z12, skip_Wb, skipS, 0);
    }

    skip_slot<false><<<sgrid, 256, 0, stream>>>(z12, skip_Wb, skipS, 12);

    head_mfma<<<dim3(LL / 32, BB), 256, 0, stream>>>(skipS, sbsum, W1b, W2b, out);
}

// Round 12
// 562.720 us; speedup vs baseline: 1.1288x; 1.1288x over previous
//
#include <hip/hip_runtime.h>
#include <math.h>

#define MU1   256
#define H     64
#define H2    128
#define SKIPC 256
#define NL    24
#define LF    80
#define UPK   4
#define REP   75
#define BB    2
#define LLEN  64
#define LL    19200

using bf16x8 = __attribute__((ext_vector_type(8))) short;
using bf16x4 = __attribute__((ext_vector_type(4))) short;
using f32x4  = __attribute__((ext_vector_type(4))) float;

__device__ __forceinline__ float b2f(short s) {
    union { unsigned u; float f; } v; v.u = ((unsigned)(unsigned short)s) << 16; return v.f;
}
__device__ __forceinline__ short f2b(float f) {
    union { float f; unsigned u; } v; v.f = f;
    unsigned r = (v.u + 0x7fff + ((v.u >> 16) & 1)) >> 16;
    return (short)r;
}

// ---------------------------------------------------------------- prep ----
__global__ __launch_bounds__(256) void prep_kernel(
    const float* __restrict__ dil_W,  const float* __restrict__ skip_W,
    const float* __restrict__ res_W,  const float* __restrict__ embed_W,
    const float* __restrict__ embed_b,const float* __restrict__ cond_W,
    const float* __restrict__ out_W1, const float* __restrict__ out_W2,
    const float* __restrict__ skip_b,
    short* __restrict__ dil_Wb, short* __restrict__ sWt,
    short* __restrict__ res_Wb, short* __restrict__ embed_allb,
    float* __restrict__ cond_Wt, short* __restrict__ W1b,
    short* __restrict__ W2b, float* __restrict__ sbsum)
{
    int idx = blockIdx.x * 256 + threadIdx.x;
    const int n1 = NL * 2 * H2 * H;     // dil_Wb[i][k][o][c]
    const int n2 = 12 * 256 * 128;      // sWt[ck][s][kc], kc=(sublayer,c)
    const int n3 = (NL - 1) * H * H;    // res_Wb[i][o][c]
    const int n4 = MU1 * H;             // embed_allb[g][h]
    const int n5 = LF * NL * H2;        // cond_Wt[c][o]
    const int n6 = MU1 * SKIPC;
    const int n7 = MU1 * MU1;
    if (idx < n1) {
        int c = idx & 63; int o = (idx >> 6) & 127;
        int k = (idx >> 13) & 1; int i = idx >> 14;
        dil_Wb[idx] = f2b(dil_W[((i * H2 + o) * H + c) * 2 + k]);
        return;
    }
    idx -= n1;
    if (idx < n2) {
        int kc = idx & 127; int s = (idx >> 7) & 255; int ck = idx >> 15;
        sWt[idx] = f2b(skip_W[((2 * ck + (kc >> 6)) * SKIPC + s) * H + (kc & 63)]);
        return;
    }
    idx -= n2;
    if (idx < n3) { res_Wb[idx] = f2b(res_W[idx]); return; }
    idx -= n3;
    if (idx < n4) {
        int h = idx & 63; int g = idx >> 6;
        embed_allb[idx] = f2b(embed_W[h * MU1 + g] + embed_b[h]);
        return;
    }
    idx -= n4;
    if (idx < n5) {
        int o = idx % (NL * H2); int c = idx / (NL * H2);
        cond_Wt[idx] = cond_W[o * LF + c];
        return;
    }
    idx -= n5;
    if (idx < n6) { W1b[idx] = f2b(out_W1[idx]); return; }
    idx -= n6;
    if (idx < n7) { W2b[idx] = f2b(out_W2[idx]); return; }
    idx -= n7;
    if (idx < SKIPC) {
        float a = 0.f;
        for (int i = 0; i < NL; i++) a += skip_b[i * SKIPC + idx];
        sbsum[idx] = a;
        return;
    }
}

// --------------------------------------------------------------- embed ----
__global__ __launch_bounds__(256) void embed_kernel(
    const int* __restrict__ gold, const short* __restrict__ eW,
    short* __restrict__ sig)
{
    int idx = blockIdx.x * 256 + threadIdx.x;
    if (idx >= BB * LL * 8) return;
    int ch = idx & 7; int bt = idx >> 3;
    int g = gold[bt];
    *(bf16x8*)(sig + (size_t)bt * H + ch * 8) = *(const bf16x8*)(eW + g * H + ch * 8);
}

// ---------------------------------------------------------------- cond ----
__global__ __launch_bounds__(256) void cond_kernel(
    const float* __restrict__ lf, const float* __restrict__ up_W,
    const float* __restrict__ up_b, const float* __restrict__ cond_Wt,
    const float* __restrict__ cond_b, const float* __restrict__ dil_b,
    float* __restrict__ condS)
{
    __shared__ float s_up[LF];
    int j = blockIdx.x;
    int ot = blockIdx.y;
    int b = blockIdx.z;
    int frame = j >> 2, k = j & 3;
    int tid = threadIdx.x;
    if (tid < LF) {
        float a = up_b[tid];
        const float* lfr = lf + (b * LLEN + frame) * LF;
        #pragma unroll 8
        for (int c = 0; c < LF; ++c) a += lfr[c] * up_W[(c * LF + tid) * UPK + k];
        s_up[tid] = a;
    }
    __syncthreads();
    int o = ot * 256 + tid;
    float a = cond_b[o] + dil_b[o];
    #pragma unroll 8
    for (int c = 0; c < LF; ++c) a += cond_Wt[c * 3072 + o] * s_up[c];
    condS[((size_t)(b * 256 + j)) * 3072 + o] = a;
}

// ---------------------------------------------------- fused layer pair ----
// R4 measured-best structure (TT=96). Single change: weight fragments are
// PRELOADED into register arrays before each MFMA chain, with
// __launch_bounds__(256,2) granting the 256-VGPR budget (still 2 blocks/CU,
// LDS-limited) so the 32 L2 loads pipeline instead of serializing.
template<int DA, int DB, bool LASTPAIR>
__global__ __launch_bounds__(256, 2) void pair_mfma(
    const short* __restrict__ sig_in, short* __restrict__ sig_out,
    short* __restrict__ z12,
    const short* __restrict__ dil_Wb_all,
    const short* __restrict__ res_Wb_all,
    const float* __restrict__ res_b_all,
    const float* __restrict__ condS,
    int p, int slot)
{
    __shared__ __align__(16) short sa[144][72];   // input rows [t0-48, t0+96)
    __shared__ __align__(16) short sb[128][72];   // A output rows [t0-32, t0+96)
    __shared__ __align__(16) short sz[128][72];   // z scratch
    __shared__ float scond[2][3][128];

    const int iA = 2 * p, iB = 2 * p + 1;
    const int b = blockIdx.y;
    const int t0 = blockIdx.x * 96;
    const int tid = threadIdx.x;
    const int w = tid >> 6;
    const int lane = tid & 63;
    const int lr = lane & 15, lg = lane >> 4;
    const int c0 = (t0 >= 32) ? (t0 - 32) / 75 : 0;

    // ---- preload A-phase weights (32 fragments, all loads in flight) ----
    const short* dWA = dil_Wb_all + (size_t)iA * 2 * H2 * H;
    bf16x8 bwA[8][4];
    #pragma unroll
    for (int n = 0; n < 8; ++n)
        #pragma unroll
        for (int kk = 0; kk < 4; ++kk)
            bwA[n][kk] = *(const bf16x8*)(dWA + (((kk >> 1) * H2 + 16 * n + lr) * H) + (kk & 1) * 32 + lg * 8);

    // ---- stage input + cond ----
    {
        const short* basein = sig_in + (size_t)b * LL * H;
        #pragma unroll
        for (int it = 0; it < 5; ++it) {
            int task = tid + it * 256;
            if (task < 1152) {
                int r = task >> 3, ch = task & 7;
                int t = t0 - 48 + r;
                bf16x8 v = {};
                if (t >= 0) v = *(const bf16x8*)(basein + (size_t)t * H + ch * 8);
                *(bf16x8*)&sa[r][ch * 8] = v;
            }
        }
        #pragma unroll
        for (int it = 0; it < 3; ++it) {
            int task = tid + it * 256;      // 768 = 2 sel x 3 col x 128
            int sel = task >= 384;
            int cj = (task - sel * 384) >> 7;
            int o = task & 127;
            int col = c0 + cj; col = col > 255 ? 255 : col;
            scond[sel][cj][o] = condS[((size_t)(b * 256 + col)) * 3072 + (iA + sel) * 128 + o];
        }
    }
    __syncthreads();

    // ---- A gated GEMM: M=128 (2 Mtiles/wave), N=128, K=128 ----
    {
        f32x4 acc[2][8];
        #pragma unroll
        for (int m = 0; m < 2; ++m)
            #pragma unroll
            for (int n = 0; n < 8; ++n) acc[m][n] = (f32x4){0.f, 0.f, 0.f, 0.f};
        bf16x8 afA[2][4];
        #pragma unroll
        for (int m = 0; m < 2; ++m) {
            int rc = 16 + 16 * (2 * w + m) + lr;
            afA[m][0] = *(const bf16x8*)&sa[rc - DA][lg * 8];
            afA[m][1] = *(const bf16x8*)&sa[rc - DA][32 + lg * 8];
            afA[m][2] = *(const bf16x8*)&sa[rc][lg * 8];
            afA[m][3] = *(const bf16x8*)&sa[rc][32 + lg * 8];
        }
        #pragma unroll
        for (int n = 0; n < 8; ++n)
            #pragma unroll
            for (int kk = 0; kk < 4; ++kk) {
                acc[0][n] = __builtin_amdgcn_mfma_f32_16x16x32_bf16(afA[0][kk], bwA[n][kk], acc[0][n], 0, 0, 0);
                acc[1][n] = __builtin_amdgcn_mfma_f32_16x16x32_bf16(afA[1][kk], bwA[n][kk], acc[1][n], 0, 0, 0);
            }
        #pragma unroll
        for (int m = 0; m < 2; ++m)
            #pragma unroll
            for (int n = 0; n < 4; ++n)
                #pragma unroll
                for (int r = 0; r < 4; ++r) {
                    int relt = -32 + 16 * (2 * w + m) + 4 * lg + r;
                    int t = t0 + relt;
                    int o = 16 * n + lr;
                    short zb = 0;
                    if (t >= 0) {
                        int ci = t / 75 - c0;
                        float av = acc[m][n][r] + scond[0][ci][o];
                        float gv = acc[m][n + 4][r] + scond[0][ci][64 + o];
                        float th = 1.f - 2.f / (__expf(2.f * av) + 1.f);
                        float sg = 1.f / (1.f + __expf(-gv));
                        zb = f2b(th * sg);
                    }
                    sz[relt + 32][o] = zb;
                }
    }
    __syncthreads();

    // z_A -> z12 slot, sub 0 (rows [0,96))
    #pragma unroll
    for (int it = 0; it < 3; ++it) {
        int task = tid + it * 256;
        int r = task >> 3, ch = task & 7;
        *(bf16x8*)(z12 + ((size_t)((slot * BB + b) * LL) + t0 + r) * 128 + ch * 8)
            = *(const bf16x8*)&sz[32 + r][ch * 8];
    }

    // ---- A residual: sb = sa + z @ rW + rb (weights preloaded) ----
    {
        const short* rW = res_Wb_all + (size_t)iA * H * H;
        const float* rb_ = res_b_all + (size_t)iA * H;
        bf16x8 bwr[4][2];
        #pragma unroll
        for (int n = 0; n < 4; ++n) {
            bwr[n][0] = *(const bf16x8*)(rW + (16 * n + lr) * H + lg * 8);
            bwr[n][1] = *(const bf16x8*)(rW + (16 * n + lr) * H + 32 + lg * 8);
        }
        f32x4 rac[2][4];
        #pragma unroll
        for (int m = 0; m < 2; ++m)
            #pragma unroll
            for (int n = 0; n < 4; ++n) rac[m][n] = (f32x4){0.f, 0.f, 0.f, 0.f};
        bf16x8 za[2][2];
        #pragma unroll
        for (int m = 0; m < 2; ++m) {
            int row = 16 * (2 * w + m) + lr;
            za[m][0] = *(const bf16x8*)&sz[row][lg * 8];
            za[m][1] = *(const bf16x8*)&sz[row][32 + lg * 8];
        }
        #pragma unroll
        for (int n = 0; n < 4; ++n)
            #pragma unroll
            for (int kk = 0; kk < 2; ++kk) {
                rac[0][n] = __builtin_amdgcn_mfma_f32_16x16x32_bf16(za[0][kk], bwr[n][kk], rac[0][n], 0, 0, 0);
                rac[1][n] = __builtin_amdgcn_mfma_f32_16x16x32_bf16(za[1][kk], bwr[n][kk], rac[1][n], 0, 0, 0);
            }
        #pragma unroll
        for (int n = 0; n < 4; ++n) {
            float rbv = rb_[16 * n + lr];
            #pragma unroll
            for (int m = 0; m < 2; ++m)
                #pragma unroll
                for (int r = 0; r < 4; ++r) {
                    int relt = -32 + 16 * (2 * w + m) + 4 * lg + r;
                    int t = t0 + relt;
                    int c = 16 * n + lr;
                    short vb = 0;
                    if (t >= 0) vb = f2b(b2f(sa[relt + 48][c]) + rac[m][n][r] + rbv);
                    sb[relt + 32][c] = vb;
                }
        }
    }
    __syncthreads();

    // ---- B gated GEMM: M=96 (6 Mtiles), wave w -> out channels (w, w+4) ----
    {
        const short* dW = dil_Wb_all + (size_t)iB * 2 * H2 * H;
        f32x4 accF[6], accG[6];
        #pragma unroll
        for (int m = 0; m < 6; ++m) { accF[m] = (f32x4){0.f,0.f,0.f,0.f}; accG[m] = (f32x4){0.f,0.f,0.f,0.f}; }
        bf16x8 bwF[4], bwG[4];
        #pragma unroll
        for (int kk = 0; kk < 4; ++kk) {
            int oF = 16 * w + lr;
            bwF[kk] = *(const bf16x8*)(dW + (((kk >> 1) * H2 + oF) * H) + (kk & 1) * 32 + lg * 8);
            bwG[kk] = *(const bf16x8*)(dW + (((kk >> 1) * H2 + 64 + oF) * H) + (kk & 1) * 32 + lg * 8);
        }
        #pragma unroll
        for (int m = 0; m < 6; ++m) {
            int rc = 32 + 16 * m + lr;
            bf16x8 af[4];
            af[0] = *(const bf16x8*)&sb[rc - DB][lg * 8];
            af[1] = *(const bf16x8*)&sb[rc - DB][32 + lg * 8];
            af[2] = *(const bf16x8*)&sb[rc][lg * 8];
            af[3] = *(const bf16x8*)&sb[rc][32 + lg * 8];
            #pragma unroll
            for (int kk = 0; kk < 4; ++kk)
                accF[m] = __builtin_amdgcn_mfma_f32_16x16x32_bf16(af[kk], bwF[kk], accF[m], 0, 0, 0);
            #pragma unroll
            for (int kk = 0; kk < 4; ++kk)
                accG[m] = __builtin_amdgcn_mfma_f32_16x16x32_bf16(af[kk], bwG[kk], accG[m], 0, 0, 0);
        }
        #pragma unroll
        for (int m = 0; m < 6; ++m)
            #pragma unroll
            for (int r = 0; r < 4; ++r) {
                int relt = 16 * m + 4 * lg + r;
                int t = t0 + relt;
                int o = 16 * w + lr;
                int ci = t / 75 - c0;
                float av = accF[m][r] + scond[1][ci][o];
                float gv = accG[m][r] + scond[1][ci][64 + o];
                float th = 1.f - 2.f / (__expf(2.f * av) + 1.f);
                float sg = 1.f / (1.f + __expf(-gv));
                sz[relt][o] = f2b(th * sg);
            }
    }
    __syncthreads();

    // z_B -> z12 slot, sub 1 (rows [0,96))
    #pragma unroll
    for (int it = 0; it < 3; ++it) {
        int task = tid + it * 256;
        int r = task >> 3, ch = task & 7;
        *(bf16x8*)(z12 + ((size_t)((slot * BB + b) * LL) + t0 + r) * 128 + 64 + ch * 8)
            = *(const bf16x8*)&sz[r][ch * 8];
    }

    // ---- B residual -> sig_out (rows [0,96)), wave w -> Ntile w ----
    if (!LASTPAIR) {
        const short* rW = res_Wb_all + (size_t)iB * H * H;
        const float* rb_ = res_b_all + (size_t)iB * H;
        int c = 16 * w + lr;
        f32x4 rac[6];
        #pragma unroll
        for (int m = 0; m < 6; ++m) rac[m] = (f32x4){0.f, 0.f, 0.f, 0.f};
        bf16x8 bwR[2];
        bwR[0] = *(const bf16x8*)(rW + c * H + lg * 8);
        bwR[1] = *(const bf16x8*)(rW + c * H + 32 + lg * 8);
        #pragma unroll
        for (int m = 0; m < 6; ++m) {
            bf16x8 z0 = *(const bf16x8*)&sz[16 * m + lr][lg * 8];
            bf16x8 z1 = *(const bf16x8*)&sz[16 * m + lr][32 + lg * 8];
            rac[m] = __builtin_amdgcn_mfma_f32_16x16x32_bf16(z0, bwR[0], rac[m], 0, 0, 0);
            rac[m] = __builtin_amdgcn_mfma_f32_16x16x32_bf16(z1, bwR[1], rac[m], 0, 0, 0);
        }
        float rbv = rb_[c];
        #pragma unroll
        for (int m = 0; m < 6; ++m)
            #pragma unroll
            for (int r = 0; r < 4; ++r) {
                int relt = 16 * m + 4 * lg + r;
                sa[relt][c] = f2b(b2f(sb[relt + 32][c]) + rac[m][r] + rbv);
            }
        __syncthreads();
        #pragma unroll
        for (int it = 0; it < 3; ++it) {
            int task = tid + it * 256;
            int r = task >> 3, ch = task & 7;
            *(bf16x8*)(sig_out + ((size_t)(b * LL + t0 + r)) * H + ch * 8)
                = *(const bf16x8*)&sa[r][ch * 8];
        }
    }
}

// -------------------------------------------------- skip (layers 0-11) ----
__global__ __launch_bounds__(256) void skip12_kernel(
    const short* __restrict__ z12, const short* __restrict__ sWt,
    short* __restrict__ skipP)
{
    __shared__ __align__(16) short s_a[2][64][136];
    const int b = blockIdx.y;
    const int t0 = blockIdx.x * 64;
    const int tid = threadIdx.x;
    const int w = tid >> 6;
    const int lane = tid & 63;
    const int lr = lane & 15, lg = lane >> 4;

    f32x4 acc[4][4];
    #pragma unroll
    for (int mt = 0; mt < 4; ++mt)
        #pragma unroll
        for (int nt = 0; nt < 4; ++nt) acc[mt][nt] = (f32x4){0.f, 0.f, 0.f, 0.f};

    #pragma unroll
    for (int it = 0; it < 4; ++it) {
        int task = tid + it * 256;
        int r = task >> 4, ch = task & 15;
        *(bf16x8*)&s_a[0][r][ch * 8] =
            *(const bf16x8*)(z12 + ((size_t)(b * LL) + t0 + r) * 128 + ch * 8);
    }
    __syncthreads();

    for (int ck = 0; ck < 6; ++ck) {
        if (ck < 5) {
            #pragma unroll
            for (int it = 0; it < 4; ++it) {
                int task = tid + it * 256;
                int r = task >> 4, ch = task & 15;
                *(bf16x8*)&s_a[(ck + 1) & 1][r][ch * 8] =
                    *(const bf16x8*)(z12 + ((size_t)(((ck + 1) * BB + b) * LL) + t0 + r) * 128 + ch * 8);
            }
        }
        const short* wbase = sWt + ((size_t)ck << 15);
        const short (*buf)[136] = s_a[ck & 1];
        #pragma unroll
        for (int kk = 0; kk < 4; ++kk) {
            bf16x8 afr[4];
            #pragma unroll
            for (int mt = 0; mt < 4; ++mt)
                afr[mt] = *(const bf16x8*)&buf[16 * mt + lr][32 * kk + 8 * lg];
            #pragma unroll
            for (int nt = 0; nt < 4; ++nt) {
                bf16x8 bw = *(const bf16x8*)(wbase + ((64 * w + 16 * nt + lr) << 7) + 32 * kk + 8 * lg);
                #pragma unroll
                for (int mt = 0; mt < 4; ++mt)
                    acc[mt][nt] = __builtin_amdgcn_mfma_f32_16x16x32_bf16(afr[mt], bw, acc[mt][nt], 0, 0, 0);
            }
        }
        __syncthreads();
    }

    #pragma unroll
    for (int mt = 0; mt < 4; ++mt)
        #pragma unroll
        for (int nt = 0; nt < 4; ++nt) {
            int s = 64 * w + 16 * nt + lr;
            #pragma unroll
            for (int reg = 0; reg < 4; ++reg) {
                int t = t0 + 16 * mt + 4 * lg + reg;
                skipP[((size_t)(b * LL) + t) * 256 + s] = f2b(acc[mt][nt][reg]);
            }
        }
}

// --------------------------------- fused skip (12-23) + output head ----
__global__ __launch_bounds__(256) void skiphead_kernel(
    const short* __restrict__ z12, const short* __restrict__ sWt,
    const short* __restrict__ skipP, const float* __restrict__ sbsum,
    const short* __restrict__ W1b, const short* __restrict__ W2b,
    float* __restrict__ out)
{
    __shared__ __align__(16) unsigned char smem[36864];
    short (*s_ab)[64][136] = (short(*)[64][136])smem;
    short (*s_x)[264] = (short(*)[264])smem;
    float (*s_o)[68]  = (float(*)[68])smem;
    __shared__ float s_red[4][64];
    __shared__ float s_sb[256];

    const int b = blockIdx.y;
    const int t0 = blockIdx.x * 64;
    const int tid = threadIdx.x;
    const int w = tid >> 6;
    const int lane = tid & 63;
    const int lr = lane & 15, lg = lane >> 4;

    s_sb[tid] = sbsum[tid];

    f32x4 acc[4][4];
    #pragma unroll
    for (int mt = 0; mt < 4; ++mt)
        #pragma unroll
        for (int nt = 0; nt < 4; ++nt) acc[mt][nt] = (f32x4){0.f, 0.f, 0.f, 0.f};

    #pragma unroll
    for (int it = 0; it < 4; ++it) {
        int task = tid + it * 256;
        int r = task >> 4, ch = task & 15;
        *(bf16x8*)&s_ab[0][r][ch * 8] =
            *(const bf16x8*)(z12 + ((size_t)(b * LL) + t0 + r) * 128 + ch * 8);
    }
    __syncthreads();
    for (int ck = 0; ck < 6; ++ck) {
        if (ck < 5) {
            #pragma unroll
            for (int it = 0; it < 4; ++it) {
                int task = tid + it * 256;
                int r = task >> 4, ch = task & 15;
                *(bf16x8*)&s_ab[(ck + 1) & 1][r][ch * 8] =
                    *(const bf16x8*)(z12 + ((size_t)(((ck + 1) * BB + b) * LL) + t0 + r) * 128 + ch * 8);
            }
        }
        const short* wbase = sWt + ((size_t)(6 + ck) << 15);
        const short (*buf)[136] = s_ab[ck & 1];
        #pragma unroll
        for (int kk = 0; kk < 4; ++kk) {
            bf16x8 afr[4];
            #pragma unroll
            for (int mt = 0; mt < 4; ++mt)
                afr[mt] = *(const bf16x8*)&buf[16 * mt + lr][32 * kk + 8 * lg];
            #pragma unroll
            for (int nt = 0; nt < 4; ++nt) {
                bf16x8 bw = *(const bf16x8*)(wbase + ((64 * w + 16 * nt + lr) << 7) + 32 * kk + 8 * lg);
                #pragma unroll
                for (int mt = 0; mt < 4; ++mt)
                    acc[mt][nt] = __builtin_amdgcn_mfma_f32_16x16x32_bf16(afr[mt], bw, acc[mt][nt], 0, 0, 0);
            }
        }
        __syncthreads();
    }

    #pragma unroll
    for (int it = 0; it < 8; ++it) {
        int task = tid + it * 256;
        int r = task >> 5, ch = task & 31;
        *(bf16x8*)&s_x[r][ch * 8] =
            *(const bf16x8*)(skipP + ((size_t)(b * LL) + t0 + r) * 256 + ch * 8);
    }
    __syncthreads();
    #pragma unroll
    for (int mt = 0; mt < 4; ++mt)
        #pragma unroll
        for (int nt = 0; nt < 4; ++nt) {
            int s = 64 * w + 16 * nt + lr;
            #pragma unroll
            for (int reg = 0; reg < 4; ++reg) {
                int tl = 16 * mt + 4 * lg + reg;
                float v = acc[mt][nt][reg] + b2f(s_x[tl][s]) + s_sb[s];
                s_x[tl][s] = f2b(fmaxf(v, 0.f));
            }
        }
    __syncthreads();

    f32x4 acc1[4][4];
    #pragma unroll
    for (int mt = 0; mt < 4; ++mt)
        #pragma unroll
        for (int nt = 0; nt < 4; ++nt) acc1[mt][nt] = (f32x4){0.f, 0.f, 0.f, 0.f};
    #pragma unroll
    for (int kk = 0; kk < 8; ++kk) {
        bf16x8 afr[4];
        #pragma unroll
        for (int mt = 0; mt < 4; ++mt)
            afr[mt] = *(const bf16x8*)&s_x[16 * mt + lr][32 * kk + 8 * lg];
        #pragma unroll
        for (int nt = 0; nt < 4; ++nt) {
            bf16x8 bw = *(const bf16x8*)(W1b + ((size_t)(64 * w + 16 * nt + lr)) * MU1 + 32 * kk + 8 * lg);
            #pragma unroll
            for (int mt = 0; mt < 4; ++mt)
                acc1[mt][nt] = __builtin_amdgcn_mfma_f32_16x16x32_bf16(afr[mt], bw, acc1[mt][nt], 0, 0, 0);
        }
    }
    __syncthreads();
    #pragma unroll
    for (int mt = 0; mt < 4; ++mt)
        #pragma unroll
        for (int nt = 0; nt < 4; ++nt)
            #pragma unroll
            for (int reg = 0; reg < 4; ++reg) {
                int tl = 16 * mt + 4 * lg + reg;
                int o = 64 * w + 16 * nt + lr;
                s_x[tl][o] = f2b(fmaxf(acc1[mt][nt][reg], 0.f));
            }
    __syncthreads();

    f32x4 acc2[4][4];
    #pragma unroll
    for (int mt = 0; mt < 4; ++mt)
        #pragma unroll
        for (int nt = 0; nt < 4; ++nt) acc2[mt][nt] = (f32x4){0.f, 0.f, 0.f, 0.f};
    #pragma unroll
    for (int kk = 0; kk < 8; ++kk) {
        bf16x8 afr[4];
        #pragma unroll
        for (int mt = 0; mt < 4; ++mt)
            afr[mt] = *(const bf16x8*)&s_x[16 * mt + lr][32 * kk + 8 * lg];
        #pragma unroll
        for (int nt = 0; nt < 4; ++nt) {
            bf16x8 bw = *(const bf16x8*)(W2b + ((size_t)(64 * w + 16 * nt + lr)) * MU1 + 32 * kk + 8 * lg);
            #pragma unroll
            for (int mt = 0; mt < 4; ++mt)
                acc2[mt][nt] = __builtin_amdgcn_mfma_f32_16x16x32_bf16(afr[mt], bw, acc2[mt][nt], 0, 0, 0);
        }
    }

    float mv[4][4];
    #pragma unroll
    for (int mt = 0; mt < 4; ++mt)
        #pragma unroll
        for (int reg = 0; reg < 4; ++reg) {
            float m = -3.4e38f;
            #pragma unroll
            for (int nt = 0; nt < 4; ++nt) m = fmaxf(m, acc2[mt][nt][reg]);
            #pragma unroll
            for (int off = 1; off <= 8; off <<= 1) m = fmaxf(m, __shfl_xor(m, off));
            int tl = 16 * mt + 4 * lg + reg;
            if (lr == 0) s_red[w][tl] = m;
        }
    __syncthreads();
    #pragma unroll
    for (int mt = 0; mt < 4; ++mt)
        #pragma unroll
        for (int reg = 0; reg < 4; ++reg) {
            int tl = 16 * mt + 4 * lg + reg;
            mv[mt][reg] = fmaxf(fmaxf(s_red[0][tl], s_red[1][tl]), fmaxf(s_red[2][tl], s_red[3][tl]));
        }
    __syncthreads();
    #pragma unroll
    for (int mt = 0; mt < 4; ++mt)
        #pragma unroll
        for (int reg = 0; reg < 4; ++reg) {
            float s = 0.f;
            #pragma unroll
            for (int nt = 0; nt < 4; ++nt) s += __expf(acc2[mt][nt][reg] - mv[mt][reg]);
            #pragma unroll
            for (int off = 1; off <= 8; off <<= 1) s += __shfl_xor(s, off);
            int tl = 16 * mt + 4 * lg + reg;
            if (lr == 0) s_red[w][tl] = s;
        }
    __syncthreads();
    #pragma unroll
    for (int mt = 0; mt < 4; ++mt)
        #pragma unroll
        for (int reg = 0; reg < 4; ++reg) {
            int tl = 16 * mt + 4 * lg + reg;
            float denom = s_red[0][tl] + s_red[1][tl] + s_red[2][tl] + s_red[3][tl];
            mv[mt][reg] = mv[mt][reg] + __logf(denom);
        }
    __syncthreads();

    #pragma unroll
    for (int pass = 0; pass < 2; ++pass) {
        if ((w >> 1) == pass) {
            #pragma unroll
            for (int mt = 0; mt < 4; ++mt)
                #pragma unroll
                for (int nt = 0; nt < 4; ++nt)
                    #pragma unroll
                    for (int reg = 0; reg < 4; ++reg) {
                        int ch = 64 * (w & 1) + 16 * nt + lr;
                        int tl = 16 * mt + 4 * lg + reg;
                        s_o[ch][tl] = acc2[mt][nt][reg] - mv[mt][reg];
                    }
        }
        __syncthreads();
        {
            int row = tid >> 1, half = tid & 1;
            float* op = out + ((size_t)(b * MU1 + pass * 128 + row)) * LL + t0 + half * 32;
            #pragma unroll
            for (int k = 0; k < 8; ++k)
                *(f32x4*)(op + 4 * k) = *(const f32x4*)&s_o[row][half * 32 + 4 * k];
        }
        __syncthreads();
    }
}

// -------------------------------------------------------------- launch ----
extern "C" void kernel_launch(void* const* d_in, const int* in_sizes, int n_in,
                              void* d_out, int out_size, void* d_ws, size_t ws_size,
                              hipStream_t stream)
{
    const float* lf      = (const float*)d_in[0];
    const int*   gold    = (const int*)  d_in[1];
    const float* embed_W = (const float*)d_in[2];
    const float* embed_b = (const float*)d_in[3];
    const float* up_W    = (const float*)d_in[4];
    const float* up_b    = (const float*)d_in[5];
    const float* cond_W  = (const float*)d_in[6];
    const float* cond_b  = (const float*)d_in[7];
    const float* dil_W   = (const float*)d_in[8];
    const float* dil_b   = (const float*)d_in[9];
    const float* skip_W  = (const float*)d_in[10];
    const float* skip_b  = (const float*)d_in[11];
    const float* res_W   = (const float*)d_in[12];
    const float* res_b   = (const float*)d_in[13];
    const float* W1      = (const float*)d_in[14];
    const float* W2      = (const float*)d_in[15];
    float* out = (float*)d_out;

    unsigned char* p = (unsigned char*)d_ws;
    short* sigA      = (short*)p; p += (size_t)BB * LL * H * 2;
    short* sigB      = (short*)p; p += (size_t)BB * LL * H * 2;
    short* z12       = (short*)p; p += (size_t)6 * BB * LL * 128 * 2;
    short* skipP     = (short*)p; p += (size_t)BB * LL * SKIPC * 2;
    float* condS     = (float*)p; p += (size_t)BB * 256 * NL * H2 * 4;
    short* dil_Wb    = (short*)p; p += (size_t)NL * 2 * H2 * H * 2;
    short* sWt       = (short*)p; p += (size_t)12 * 256 * 128 * 2;
    short* res_Wb    = (short*)p; p += (size_t)(NL - 1) * H * H * 2;
    short* embed_allb= (short*)p; p += (size_t)MU1 * H * 2;
    float* cond_Wt   = (float*)p; p += (size_t)LF * NL * H2 * 4;
    short* W1b       = (short*)p; p += (size_t)MU1 * SKIPC * 2;
    short* W2b       = (short*)p; p += (size_t)MU1 * MU1 * 2;
    float* sbsum     = (float*)p; p += (size_t)SKIPC * 4;

    const int prep_n = NL*2*H2*H + 12*256*128 + (NL-1)*H*H + MU1*H + LF*NL*H2 + MU1*SKIPC + MU1*MU1 + SKIPC;
    prep_kernel<<<(prep_n + 255) / 256, 256, 0, stream>>>(
        dil_W, skip_W, res_W, embed_W, embed_b, cond_W, W1, W2, skip_b,
        dil_Wb, sWt, res_Wb, embed_allb, cond_Wt, W1b, W2b, sbsum);

    embed_kernel<<<(BB * LL * 8 + 255) / 256, 256, 0, stream>>>(gold, embed_allb, sigA);

    cond_kernel<<<dim3(256, 12, BB), 256, 0, stream>>>(lf, up_W, up_b, cond_Wt, cond_b, dil_b, condS);

    short* si = sigA;
    short* so = sigB;
    dim3 pgrid(LL / 96, BB);   // 200 x 2
    dim3 sgrid(LL / 64, BB);   // 300 x 2
    for (int pp = 0; pp < 12; ++pp) {
        int slot = pp % 6;
        int r3 = pp % 3;
        if (r3 == 0)
            pair_mfma<1, 2, false><<<pgrid, 256, 0, stream>>>(si, so, z12, dil_Wb, res_Wb, res_b, condS, pp, slot);
        else if (r3 == 1)
            pair_mfma<4, 8, false><<<pgrid, 256, 0, stream>>>(si, so, z12, dil_Wb, res_Wb, res_b, condS, pp, slot);
        else if (pp == 11)
            pair_mfma<16, 32, true><<<pgrid, 256, 0, stream>>>(si, so, z12, dil_Wb, res_Wb, res_b, condS, pp, slot);
        else
            pair_mfma<16, 32, false><<<pgrid, 256, 0, stream>>>(si, so, z12, dil_Wb, res_Wb, res_b, condS, pp, slot);
        short* tmp = si; si = so; so = tmp;

        if (pp == 5)
            skip12_kernel<<<sgrid, 256, 0, stream>>>(z12, sWt, skipP);
    }

    skiphead_kernel<<<sgrid, 256, 0, stream>>>(z12, sWt, skipP, sbsum, W1b, W2b, out);
}